// Round 1
// baseline (26.997 us; speedup 1.0000x reference)
//
#include <hip/hip_runtime.h>
#include <hip/hip_bf16.h>

// out[b] = dot(user_factors[user_indices[b]], s) where
// s[f] = sum_c item_factors[item_indices[c], f]
// F = 64 (one wave = one feature vector).

#define FDIM 64

__global__ void mf_zero_s(float* s) {
    s[threadIdx.x] = 0.0f;
}

// 64 blocks x 256 threads: each wave (64 lanes) strides over items,
// lane = feature index. Block reduces its 4 waves in LDS, then atomicAdd.
__global__ void mf_item_sum(const int* __restrict__ item_idx,
                            const float* __restrict__ item_factors,
                            float* __restrict__ s, int B) {
    const int lane = threadIdx.x & 63;
    const int wavesPerBlock = blockDim.x >> 6;
    const int gwave = blockIdx.x * wavesPerBlock + (threadIdx.x >> 6);
    const int nwaves = gridDim.x * wavesPerBlock;

    float acc = 0.0f;
    for (int i = gwave; i < B; i += nwaves) {
        const int idx = item_idx[i];
        acc += item_factors[(long long)idx * FDIM + lane];
    }

    __shared__ float red[256];
    red[threadIdx.x] = acc;
    __syncthreads();
    if (threadIdx.x < FDIM) {
        float v = red[threadIdx.x] + red[threadIdx.x + 64] +
                  red[threadIdx.x + 128] + red[threadIdx.x + 192];
        atomicAdd(&s[threadIdx.x], v);
    }
}

// One wave per output element: lane f loads u[f]*s[f], shuffle-reduce, lane 0 writes.
__global__ void mf_user_dot(const int* __restrict__ user_idx,
                            const float* __restrict__ user_factors,
                            const float* __restrict__ s,
                            float* __restrict__ out, int B) {
    const int lane = threadIdx.x & 63;
    const int b = blockIdx.x * (blockDim.x >> 6) + (threadIdx.x >> 6);
    if (b >= B) return;
    const int idx = user_idx[b];
    float v = user_factors[(long long)idx * FDIM + lane] * s[lane];
    // 64-lane butterfly reduce
    v += __shfl_down(v, 32);
    v += __shfl_down(v, 16);
    v += __shfl_down(v, 8);
    v += __shfl_down(v, 4);
    v += __shfl_down(v, 2);
    v += __shfl_down(v, 1);
    if (lane == 0) out[b] = v;
}

extern "C" void kernel_launch(void* const* d_in, const int* in_sizes, int n_in,
                              void* d_out, int out_size, void* d_ws, size_t ws_size,
                              hipStream_t stream) {
    const int* user_idx = (const int*)d_in[0];
    const int* item_idx = (const int*)d_in[1];
    const float* user_factors = (const float*)d_in[2];
    const float* item_factors = (const float*)d_in[3];
    float* out = (float*)d_out;
    float* s = (float*)d_ws;  // 64 floats of scratch

    const int B = in_sizes[0];

    mf_zero_s<<<1, FDIM, 0, stream>>>(s);
    mf_item_sum<<<64, 256, 0, stream>>>(item_idx, item_factors, s, B);

    const int wavesPerBlock = 4;  // 256 threads
    const int nblocks = (B + wavesPerBlock - 1) / wavesPerBlock;
    mf_user_dot<<<nblocks, 256, 0, stream>>>(user_idx, user_factors, s, out, B);
}